// Round 8
// baseline (243.270 us; speedup 1.0000x reference)
//
#include <hip/hip_runtime.h>
#include <math.h>

#define L_SEQ 32768
#define H_DIM 512
#define P_DIM 256
#define K_DIM 512
#define CHUNK 32
#define NCHUNK (L_SEQ / CHUNK)   // 1024

typedef __bf16 bf16x8 __attribute__((ext_vector_type(8)));
typedef float floatx4 __attribute__((ext_vector_type(4)));

__device__ __forceinline__ void gll16(const void* g, void* l) {
    __builtin_amdgcn_global_load_lds(
        (__attribute__((address_space(1))) void*)(g),
        (__attribute__((address_space(3))) void*)(l), 16, 0, 0);
}

// Fused builders (proven r5/r7).
__global__ __launch_bounds__(512) void build_kernel(
    const float* __restrict__ Bre, const float* __restrict__ Bim,
    const float* __restrict__ Cre, const float* __restrict__ Cim,
    __bf16* __restrict__ B2, __bf16* __restrict__ C2)
{
    const int b = blockIdx.x;
    const int t = threadIdx.x;
    if (b < 256) {
        B2[(2 * b) * 512 + t]     = (__bf16)Bre[b * H_DIM + t];
        B2[(2 * b + 1) * 512 + t] = (__bf16)Bim[b * H_DIM + t];
    } else {
        const int h = b - 256;
        const int p = t & 255;
        if (t < 256)
            C2[h * 512 + 2 * p]     = (__bf16)Cre[h * P_DIM + p];
        else
            C2[h * 512 + 2 * p + 1] = (__bf16)(-Cim[h * P_DIM + p]);
    }
}

// ---------------------------------------------------------------------------
// GEMM1 (r0-exact, proven 52 us): G2[l,j] = sum_h U[l,h]*B2[j,h].
// ---------------------------------------------------------------------------
__global__ __launch_bounds__(256) void gemm1_kernel(
    const float* __restrict__ A,     // L x 512 fp32 (U)
    const __bf16* __restrict__ Bm,   // 512 x 512 bf16 (B2)
    __bf16* __restrict__ Out)        // L x 512 bf16 (G2)
{
    __shared__ float  Asf[128 * 32];   // 16 KB
    __shared__ __bf16 Bs [128 * 32];   // 8 KB

    const int tid = threadIdx.x;
    const int w  = tid >> 6;
    const int ln = tid & 63;
    const int bm = blockIdx.x;
    const int bn = blockIdx.y;

    floatx4 acc[4][4];
    #pragma unroll
    for (int i = 0; i < 4; ++i)
        #pragma unroll
        for (int j = 0; j < 4; ++j)
            acc[i][j] = (floatx4){0.f, 0.f, 0.f, 0.f};

    const int a_r = ln >> 3;
    const int a_c = (ln & 7) << 2;
    const int b_r = ln >> 2;
    const int b_c = (ln & 3) << 3;
    const size_t brow = (size_t)(bn * 128 + w * 16 + b_r) * K_DIM;

    float*  lA[4];
    size_t  gAr[4];
    #pragma unroll
    for (int q = 0; q < 4; ++q) {
        lA[q] = Asf + (q * 32 + w * 8) * 32;
        gAr[q] = (size_t)(bm * 128 + q * 32 + w * 8 + a_r) * K_DIM;
    }
    __bf16* lB0 = Bs + w * 512;
    __bf16* lB1 = Bs + 2048 + w * 512;

    const int wm = (w >> 1) * 64;
    const int wn = (w & 1) * 64;
    const int fr = ln & 15;
    const int fq = (ln >> 4) * 8;

    for (int kt = 0; kt < K_DIM; kt += 32) {
        __syncthreads();
        #pragma unroll
        for (int q = 0; q < 4; ++q)
            gll16(A + gAr[q] + kt + a_c, lA[q]);
        gll16(Bm + brow + kt + b_c,                      lB0);
        gll16(Bm + brow + (size_t)64 * K_DIM + kt + b_c, lB1);
        __syncthreads();

        bf16x8 a[4], b[4];
        #pragma unroll
        for (int mt = 0; mt < 4; ++mt) {
            floatx4 a0 = *(floatx4*)&Asf[(wm + mt * 16 + fr) * 32 + fq];
            floatx4 a1 = *(floatx4*)&Asf[(wm + mt * 16 + fr) * 32 + fq + 4];
            #pragma unroll
            for (int r = 0; r < 4; ++r) {
                a[mt][r]     = (__bf16)a0[r];
                a[mt][4 + r] = (__bf16)a1[r];
            }
        }
        #pragma unroll
        for (int nt = 0; nt < 4; ++nt)
            b[nt] = *(bf16x8*)&Bs[(wn + nt * 16 + fr) * 32 + fq];

        #pragma unroll
        for (int mt = 0; mt < 4; ++mt)
            #pragma unroll
            for (int nt = 0; nt < 4; ++nt)
                acc[mt][nt] = __builtin_amdgcn_mfma_f32_16x16x32_bf16(
                    a[mt], b[nt], acc[mt][nt], 0, 0, 0);
    }

    const int rq = (ln >> 4) * 4;
    #pragma unroll
    for (int mt = 0; mt < 4; ++mt) {
        const int gro = bm * 128 + wm + mt * 16 + rq;
        #pragma unroll
        for (int nt = 0; nt < 4; ++nt) {
            const int gco = bn * 128 + wn + nt * 16 + (ln & 15);
            #pragma unroll
            for (int r = 0; r < 4; ++r)
                Out[(size_t)(gro + r) * 512 + gco] = (__bf16)acc[mt][nt][r];
        }
    }
}

// ---------------------------------------------------------------------------
// GEMM2: out = 2 * X2 * C2^T + D*u.  NEW: 256x256 tile, BK=64, 8 waves,
// double-buffered 2-phase pipeline (T3-minimum recipe):
//   prologue: stage(0, buf0); barrier
//   t: stage(t+1, nxt); compute(cur); barrier      (one barrier per K-step)
// LDS 128 KB (2 x (32KB A + 32KB B)).  Per wave per K-step: 64 MFMA.
// ---------------------------------------------------------------------------
__global__ __launch_bounds__(512, 2) void gemm2_kernel(
    const __bf16* __restrict__ A,    // L x 512 bf16 (X2)
    const __bf16* __restrict__ Bm,   // 512 x 512 bf16 (C2)
    float* __restrict__ Out,         // L x 512 fp32
    const float* __restrict__ U,
    const float* __restrict__ Dv)
{
    __shared__ __bf16 As[2][256 * 64];   // 32 KB each
    __shared__ __bf16 Bs[2][256 * 64];   // 32 KB each

    const int tid = threadIdx.x;
    const int w  = tid >> 6;        // 0..7
    const int ln = tid & 63;
    const int bm = blockIdx.x;      // 0..127
    const int bn = blockIdx.y;      // 0..1

    const int wr = w >> 2;          // 0..1 : row half (128 rows)
    const int wc = w & 3;           // 0..3 : col quarter (64 cols)

    floatx4 acc[8][4];
    #pragma unroll
    for (int i = 0; i < 8; ++i)
        #pragma unroll
        for (int j = 0; j < 4; ++j)
            acc[i][j] = (floatx4){0.f, 0.f, 0.f, 0.f};

    // staging: per gll16 a wave covers 8 rows (8 lanes/row, 16B each)
    const int srow = ln >> 3;             // 0..7
    const int scol = (ln & 7) << 3;       // 0..56 (bf16 elems)
    const size_t agbase = (size_t)(bm * 256 + w * 8 + srow) * K_DIM + scol;
    const size_t bgbase = (size_t)(bn * 256 + w * 8 + srow) * K_DIM + scol;

    const int fr = ln & 15;
    const int fq = (ln >> 4) << 3;

    auto stage = [&](int kt, int buf) {
        #pragma unroll
        for (int q = 0; q < 4; ++q) {
            const int r0 = q * 64 + w * 8;
            gll16(A  + agbase + (size_t)q * 64 * K_DIM + kt, &As[buf][r0 * 64]);
            gll16(Bm + bgbase + (size_t)q * 64 * K_DIM + kt, &Bs[buf][r0 * 64]);
        }
    };
    auto compute = [&](int buf) {
        #pragma unroll
        for (int ks = 0; ks < 2; ++ks) {
            bf16x8 a[8], b[4];
            #pragma unroll
            for (int mt = 0; mt < 8; ++mt)
                a[mt] = *(const bf16x8*)
                    &As[buf][(wr * 128 + mt * 16 + fr) * 64 + ks * 32 + fq];
            #pragma unroll
            for (int nt = 0; nt < 4; ++nt)
                b[nt] = *(const bf16x8*)
                    &Bs[buf][(wc * 64 + nt * 16 + fr) * 64 + ks * 32 + fq];
            #pragma unroll
            for (int mt = 0; mt < 8; ++mt)
                #pragma unroll
                for (int nt = 0; nt < 4; ++nt)
                    acc[mt][nt] = __builtin_amdgcn_mfma_f32_16x16x32_bf16(
                        a[mt], b[nt], acc[mt][nt], 0, 0, 0);
        }
    };

    stage(0, 0);
    __syncthreads();

    #pragma unroll
    for (int t = 0; t < 8; ++t) {
        if (t + 1 < 8) stage((t + 1) * 64, (t + 1) & 1);
        compute(t & 1);
        __syncthreads();
    }

    const int rq = (ln >> 4) * 4;
    #pragma unroll
    for (int mt = 0; mt < 8; ++mt) {
        const int gro = bm * 256 + wr * 128 + mt * 16 + rq;
        #pragma unroll
        for (int nt = 0; nt < 4; ++nt) {
            const int gco = bn * 256 + wc * 64 + nt * 16 + (ln & 15);
            const float dh = Dv[gco];
            #pragma unroll
            for (int r = 0; r < 4; ++r) {
                const size_t o = (size_t)(gro + r) * 512 + gco;
                Out[o] = 2.0f * acc[mt][nt][r] + dh * U[o];
            }
        }
    }
}

// ---------------------------------------------------------------------------
// Chunked scan (r0-exact proven).
// ---------------------------------------------------------------------------
template <int WRITE_X>
__global__ __launch_bounds__(256) void scan_chunk_kernel(
    const float* __restrict__ dts,
    const float* __restrict__ Lre_g, const float* __restrict__ Lim_g,
    const float* __restrict__ logstep,
    unsigned int* __restrict__ G2u,   // L x 256 uints (bf16 re|im)
    float4* __restrict__ Agg,
    const float2* __restrict__ Carry)
{
    const int p = threadIdx.x;
    const int c = blockIdx.x;
    const int base = c * CHUNK;

    unsigned int g[CHUNK];
    float dt[CHUNK];
    #pragma unroll
    for (int i = 0; i < CHUNK; ++i)
        g[i] = G2u[(size_t)(base + i) * 256 + p];
    #pragma unroll
    for (int i = 0; i < CHUNK; ++i)
        dt[i] = dts[base + i];

    const float lre = Lre_g[p];
    const float lim = Lim_g[p];
    const float stp = __expf(logstep[p]);
    const float inv_den = 1.0f / (lre * lre + lim * lim);

    float Are = 1.0f, Aim = 0.0f;
    float xre, xim;
    if (WRITE_X) {
        float2 cc = Carry[c * P_DIM + p];
        xre = cc.x; xim = cc.y;
    } else {
        xre = 0.0f; xim = 0.0f;
    }

    #pragma unroll
    for (int i = 0; i < CHUNK; ++i) {
        const float d = stp * dt[i];
        const float er = __expf(lre * d);
        float sn, cs;
        __sincosf(lim * d, &sn, &cs);
        const float are = er * cs;
        const float aim = er * sn;
        const float am1 = are - 1.0f;
        const float gr = (am1 * lre + aim * lim) * inv_den;
        const float gi = (aim * lre - am1 * lim) * inv_den;

        const float ure = __uint_as_float(g[i] << 16);
        const float uim = __uint_as_float(g[i] & 0xffff0000u);
        const float bre = gr * ure - gi * uim;
        const float bim = gr * uim + gi * ure;

        const float nxre = are * xre - aim * xim + bre;
        const float nxim = are * xim + aim * xre + bim;
        xre = nxre; xim = nxim;

        if (WRITE_X) {
            __bf16 xr = (__bf16)xre;
            __bf16 xi = (__bf16)xim;
            unsigned int o = (unsigned int)*(unsigned short*)&xr |
                             ((unsigned int)*(unsigned short*)&xi << 16);
            G2u[(size_t)(base + i) * 256 + p] = o;
        } else {
            const float nAre = are * Are - aim * Aim;
            const float nAim = are * Aim + aim * Are;
            Are = nAre; Aim = nAim;
        }
    }

    if (!WRITE_X)
        Agg[p * NCHUNK + c] = make_float4(Are, Aim, xre, xim);
}

// ---------------------------------------------------------------------------
// Carry scan via shfl (proven r7).
// ---------------------------------------------------------------------------
struct CT { float Ar, Ai, br, bi; };   // x -> A*x + b  (complex)

__device__ __forceinline__ CT ct_compose(const CT& f, const CT& s) {
    CT r;
    r.Ar = s.Ar * f.Ar - s.Ai * f.Ai;
    r.Ai = s.Ar * f.Ai + s.Ai * f.Ar;
    r.br = s.Ar * f.br - s.Ai * f.bi + s.br;
    r.bi = s.Ar * f.bi + s.Ai * f.br + s.bi;
    return r;
}

__global__ __launch_bounds__(256) void carry_shfl_kernel(
    const float4* __restrict__ Agg,   // P x NCHUNK
    float2* __restrict__ Carry)       // NCHUNK x P
{
    const int pch = blockIdx.x;
    const int t  = threadIdx.x;
    const int ln = t & 63;
    const int wv = t >> 6;

    __shared__ float4 wtot[4];

    CT v[4];
    #pragma unroll
    for (int i = 0; i < 4; ++i) {
        float4 f = Agg[(size_t)pch * NCHUNK + 4 * t + i];
        v[i].Ar = f.x; v[i].Ai = f.y; v[i].br = f.z; v[i].bi = f.w;
    }
    CT val = v[0];
    #pragma unroll
    for (int i = 1; i < 4; ++i) val = ct_compose(val, v[i]);

    #pragma unroll
    for (int off = 1; off < 64; off <<= 1) {
        CT o;
        o.Ar = __shfl_up(val.Ar, off);
        o.Ai = __shfl_up(val.Ai, off);
        o.br = __shfl_up(val.br, off);
        o.bi = __shfl_up(val.bi, off);
        if (ln >= off) val = ct_compose(o, val);
    }

    CT lexcl;
    lexcl.Ar = __shfl_up(val.Ar, 1);
    lexcl.Ai = __shfl_up(val.Ai, 1);
    lexcl.br = __shfl_up(val.br, 1);
    lexcl.bi = __shfl_up(val.bi, 1);
    if (ln == 0) { lexcl.Ar = 1.f; lexcl.Ai = 0.f; lexcl.br = 0.f; lexcl.bi = 0.f; }

    if (ln == 63) wtot[wv] = make_float4(val.Ar, val.Ai, val.br, val.bi);
    __syncthreads();

    CT wpre; wpre.Ar = 1.f; wpre.Ai = 0.f; wpre.br = 0.f; wpre.bi = 0.f;
    for (int i = 0; i < wv; ++i) {
        float4 f = wtot[i];
        CT tt; tt.Ar = f.x; tt.Ai = f.y; tt.br = f.z; tt.bi = f.w;
        wpre = ct_compose(wpre, tt);
    }

    CT E = ct_compose(wpre, lexcl);
    #pragma unroll
    for (int i = 0; i < 4; ++i) {
        Carry[(size_t)(4 * t + i) * P_DIM + pch] = make_float2(E.br, E.bi);
        E = ct_compose(E, v[i]);
    }
}

extern "C" void kernel_launch(void* const* d_in, const int* in_sizes, int n_in,
                              void* d_out, int out_size, void* d_ws, size_t ws_size,
                              hipStream_t stream) {
    const float* U       = (const float*)d_in[0];
    const float* dts     = (const float*)d_in[1];
    const float* Lre     = (const float*)d_in[2];
    const float* Lim     = (const float*)d_in[3];
    const float* Bre     = (const float*)d_in[4];
    const float* Bim     = (const float*)d_in[5];
    const float* Cre     = (const float*)d_in[6];
    const float* Cim     = (const float*)d_in[7];
    const float* Dv      = (const float*)d_in[8];
    const float* logstep = (const float*)d_in[9];
    float* out = (float*)d_out;

    char* ws = (char*)d_ws;
    __bf16* G2 = (__bf16*)ws;                                 // L x 512 bf16
    __bf16* B2 = (__bf16*)(ws + (size_t)L_SEQ * 512 * 2);
    __bf16* C2 = B2 + 512 * 512;
    float4* Agg = (float4*)(C2 + 512 * 512);
    float2* Carry = (float2*)(Agg + (size_t)P_DIM * NCHUNK);

    build_kernel<<<768, 512, 0, stream>>>(Bre, Bim, Cre, Cim, B2, C2);

    dim3 g1(L_SEQ / 128, 4);
    gemm1_kernel<<<g1, 256, 0, stream>>>(U, B2, G2);

    unsigned int* G2u = (unsigned int*)G2;
    scan_chunk_kernel<0><<<NCHUNK, 256, 0, stream>>>(
        dts, Lre, Lim, logstep, G2u, Agg, nullptr);
    carry_shfl_kernel<<<P_DIM, 256, 0, stream>>>(Agg, Carry);
    scan_chunk_kernel<1><<<NCHUNK, 256, 0, stream>>>(
        dts, Lre, Lim, logstep, G2u, nullptr, Carry);

    dim3 g2(L_SEQ / 256, 2);
    gemm2_kernel<<<g2, 512, 0, stream>>>(G2, C2, out, U, Dv);
}

// Round 9
// 227.329 us; speedup vs baseline: 1.0701x; 1.0701x over previous
//
#include <hip/hip_runtime.h>
#include <math.h>

#define L_SEQ 32768
#define H_DIM 512
#define P_DIM 256
#define K_DIM 512
#define CHUNK 32
#define NCHUNK (L_SEQ / CHUNK)   // 1024

typedef __bf16 bf16x8 __attribute__((ext_vector_type(8)));
typedef float floatx4 __attribute__((ext_vector_type(4)));

__device__ __forceinline__ void gll16(const void* g, void* l) {
    __builtin_amdgcn_global_load_lds(
        (__attribute__((address_space(1))) void*)(g),
        (__attribute__((address_space(3))) void*)(l), 16, 0, 0);
}

// Fused builders (proven r5/r7).
__global__ __launch_bounds__(512) void build_kernel(
    const float* __restrict__ Bre, const float* __restrict__ Bim,
    const float* __restrict__ Cre, const float* __restrict__ Cim,
    __bf16* __restrict__ B2, __bf16* __restrict__ C2)
{
    const int b = blockIdx.x;
    const int t = threadIdx.x;
    if (b < 256) {
        B2[(2 * b) * 512 + t]     = (__bf16)Bre[b * H_DIM + t];
        B2[(2 * b + 1) * 512 + t] = (__bf16)Bim[b * H_DIM + t];
    } else {
        const int h = b - 256;
        const int p = t & 255;
        if (t < 256)
            C2[h * 512 + 2 * p]     = (__bf16)Cre[h * P_DIM + p];
        else
            C2[h * 512 + 2 * p + 1] = (__bf16)(-Cim[h * P_DIM + p]);
    }
}

// ---------------------------------------------------------------------------
// GEMM1 (r0-exact, proven 52 us): G2[l,j] = sum_h U[l,h]*B2[j,h].
// ---------------------------------------------------------------------------
__global__ __launch_bounds__(256) void gemm1_kernel(
    const float* __restrict__ A,     // L x 512 fp32 (U)
    const __bf16* __restrict__ Bm,   // 512 x 512 bf16 (B2)
    __bf16* __restrict__ Out)        // L x 512 bf16 (G2)
{
    __shared__ float  Asf[128 * 32];   // 16 KB
    __shared__ __bf16 Bs [128 * 32];   // 8 KB

    const int tid = threadIdx.x;
    const int w  = tid >> 6;
    const int ln = tid & 63;
    const int bm = blockIdx.x;
    const int bn = blockIdx.y;

    floatx4 acc[4][4];
    #pragma unroll
    for (int i = 0; i < 4; ++i)
        #pragma unroll
        for (int j = 0; j < 4; ++j)
            acc[i][j] = (floatx4){0.f, 0.f, 0.f, 0.f};

    const int a_r = ln >> 3;
    const int a_c = (ln & 7) << 2;
    const int b_r = ln >> 2;
    const int b_c = (ln & 3) << 3;
    const size_t brow = (size_t)(bn * 128 + w * 16 + b_r) * K_DIM;

    float*  lA[4];
    size_t  gAr[4];
    #pragma unroll
    for (int q = 0; q < 4; ++q) {
        lA[q] = Asf + (q * 32 + w * 8) * 32;
        gAr[q] = (size_t)(bm * 128 + q * 32 + w * 8 + a_r) * K_DIM;
    }
    __bf16* lB0 = Bs + w * 512;
    __bf16* lB1 = Bs + 2048 + w * 512;

    const int wm = (w >> 1) * 64;
    const int wn = (w & 1) * 64;
    const int fr = ln & 15;
    const int fq = (ln >> 4) * 8;

    for (int kt = 0; kt < K_DIM; kt += 32) {
        __syncthreads();
        #pragma unroll
        for (int q = 0; q < 4; ++q)
            gll16(A + gAr[q] + kt + a_c, lA[q]);
        gll16(Bm + brow + kt + b_c,                      lB0);
        gll16(Bm + brow + (size_t)64 * K_DIM + kt + b_c, lB1);
        __syncthreads();

        bf16x8 a[4], b[4];
        #pragma unroll
        for (int mt = 0; mt < 4; ++mt) {
            floatx4 a0 = *(floatx4*)&Asf[(wm + mt * 16 + fr) * 32 + fq];
            floatx4 a1 = *(floatx4*)&Asf[(wm + mt * 16 + fr) * 32 + fq + 4];
            #pragma unroll
            for (int r = 0; r < 4; ++r) {
                a[mt][r]     = (__bf16)a0[r];
                a[mt][4 + r] = (__bf16)a1[r];
            }
        }
        #pragma unroll
        for (int nt = 0; nt < 4; ++nt)
            b[nt] = *(bf16x8*)&Bs[(wn + nt * 16 + fr) * 32 + fq];

        #pragma unroll
        for (int mt = 0; mt < 4; ++mt)
            #pragma unroll
            for (int nt = 0; nt < 4; ++nt)
                acc[mt][nt] = __builtin_amdgcn_mfma_f32_16x16x32_bf16(
                    a[mt], b[nt], acc[mt][nt], 0, 0, 0);
    }

    const int rq = (ln >> 4) * 4;
    #pragma unroll
    for (int mt = 0; mt < 4; ++mt) {
        const int gro = bm * 128 + wm + mt * 16 + rq;
        #pragma unroll
        for (int nt = 0; nt < 4; ++nt) {
            const int gco = bn * 128 + wn + nt * 16 + (ln & 15);
            #pragma unroll
            for (int r = 0; r < 4; ++r)
                Out[(size_t)(gro + r) * 512 + gco] = (__bf16)acc[mt][nt][r];
        }
    }
}

// ---------------------------------------------------------------------------
// GEMM2 (r0-exact, proven ~48 us): out = 2 * X2 * C2^T + D*u.
// ---------------------------------------------------------------------------
__global__ __launch_bounds__(256) void gemm2_kernel(
    const __bf16* __restrict__ A,    // L x 512 bf16 (X2)
    const __bf16* __restrict__ Bm,   // 512 x 512 bf16 (C2)
    float* __restrict__ Out,         // L x 512 fp32
    const float* __restrict__ U,
    const float* __restrict__ Dv)
{
    __shared__ __bf16 As[128 * 32];
    __shared__ __bf16 Bs[128 * 32];

    const int tid = threadIdx.x;
    const int w  = tid >> 6;
    const int ln = tid & 63;
    const int bm = blockIdx.x;
    const int bn = blockIdx.y;

    floatx4 acc[4][4];
    #pragma unroll
    for (int i = 0; i < 4; ++i)
        #pragma unroll
        for (int j = 0; j < 4; ++j)
            acc[i][j] = (floatx4){0.f, 0.f, 0.f, 0.f};

    const int lr = ln >> 2;
    const int lce = (ln & 3) << 3;
    const size_t arow = (size_t)(bm * 128 + w * 16 + lr) * K_DIM;
    const size_t brow = (size_t)(bn * 128 + w * 16 + lr) * K_DIM;

    __bf16* lA0 = As + w * 512;
    __bf16* lA1 = As + 2048 + w * 512;
    __bf16* lB0 = Bs + w * 512;
    __bf16* lB1 = Bs + 2048 + w * 512;

    const int wm = (w >> 1) * 64;
    const int wn = (w & 1) * 64;
    const int fr = ln & 15;
    const int fq = (ln >> 4) * 8;

    for (int kt = 0; kt < K_DIM; kt += 32) {
        __syncthreads();
        gll16(A  + arow + kt + lce,                      lA0);
        gll16(A  + arow + (size_t)64 * K_DIM + kt + lce, lA1);
        gll16(Bm + brow + kt + lce,                      lB0);
        gll16(Bm + brow + (size_t)64 * K_DIM + kt + lce, lB1);
        __syncthreads();

        bf16x8 a[4], b[4];
        #pragma unroll
        for (int mt = 0; mt < 4; ++mt)
            a[mt] = *(bf16x8*)&As[(wm + mt * 16 + fr) * 32 + fq];
        #pragma unroll
        for (int nt = 0; nt < 4; ++nt)
            b[nt] = *(bf16x8*)&Bs[(wn + nt * 16 + fr) * 32 + fq];

        #pragma unroll
        for (int mt = 0; mt < 4; ++mt)
            #pragma unroll
            for (int nt = 0; nt < 4; ++nt)
                acc[mt][nt] = __builtin_amdgcn_mfma_f32_16x16x32_bf16(
                    a[mt], b[nt], acc[mt][nt], 0, 0, 0);
    }

    const int rq = (ln >> 4) * 4;
    #pragma unroll
    for (int mt = 0; mt < 4; ++mt) {
        const int gro = bm * 128 + wm + mt * 16 + rq;
        #pragma unroll
        for (int nt = 0; nt < 4; ++nt) {
            const int gco = bn * 128 + wn + nt * 16 + (ln & 15);
            const float dh = Dv[gco];
            #pragma unroll
            for (int r = 0; r < 4; ++r) {
                const size_t o = (size_t)(gro + r) * 512 + gco;
                Out[o] = 2.0f * acc[mt][nt][r] + dh * U[o];
            }
        }
    }
}

// ---------------------------------------------------------------------------
// Chunked scan.  ONLY change vs proven r7: __sincosf (which lowers to the
// PRECISE __ocml_sincos_f32, ~100+ instr with range reduction) replaced by
// native __sinf/__cosf (v_sin_f32/v_cos_f32).  Args are |lim*d| <~ 2 rad, so
// native precision (~1-2 ulp) is invisible under bf16 output rounding.
// ---------------------------------------------------------------------------
template <int WRITE_X>
__global__ __launch_bounds__(256) void scan_chunk_kernel(
    const float* __restrict__ dts,
    const float* __restrict__ Lre_g, const float* __restrict__ Lim_g,
    const float* __restrict__ logstep,
    unsigned int* __restrict__ G2u,   // L x 256 uints (bf16 re|im)
    float4* __restrict__ Agg,
    const float2* __restrict__ Carry)
{
    const int p = threadIdx.x;
    const int c = blockIdx.x;
    const int base = c * CHUNK;

    unsigned int g[CHUNK];
    float dt[CHUNK];
    #pragma unroll
    for (int i = 0; i < CHUNK; ++i)
        g[i] = G2u[(size_t)(base + i) * 256 + p];
    #pragma unroll
    for (int i = 0; i < CHUNK; ++i)
        dt[i] = dts[base + i];

    const float lre = Lre_g[p];
    const float lim = Lim_g[p];
    const float stp = __expf(logstep[p]);
    const float inv_den = 1.0f / (lre * lre + lim * lim);

    float Are = 1.0f, Aim = 0.0f;
    float xre, xim;
    if (WRITE_X) {
        float2 cc = Carry[c * P_DIM + p];
        xre = cc.x; xim = cc.y;
    } else {
        xre = 0.0f; xim = 0.0f;
    }

    #pragma unroll
    for (int i = 0; i < CHUNK; ++i) {
        const float d = stp * dt[i];
        const float er = __expf(lre * d);
        const float sn = __sinf(lim * d);
        const float cs = __cosf(lim * d);
        const float are = er * cs;
        const float aim = er * sn;
        const float am1 = are - 1.0f;
        const float gr = (am1 * lre + aim * lim) * inv_den;
        const float gi = (aim * lre - am1 * lim) * inv_den;

        const float ure = __uint_as_float(g[i] << 16);
        const float uim = __uint_as_float(g[i] & 0xffff0000u);
        const float bre = gr * ure - gi * uim;
        const float bim = gr * uim + gi * ure;

        const float nxre = are * xre - aim * xim + bre;
        const float nxim = are * xim + aim * xre + bim;
        xre = nxre; xim = nxim;

        if (WRITE_X) {
            __bf16 xr = (__bf16)xre;
            __bf16 xi = (__bf16)xim;
            unsigned int o = (unsigned int)*(unsigned short*)&xr |
                             ((unsigned int)*(unsigned short*)&xi << 16);
            G2u[(size_t)(base + i) * 256 + p] = o;
        } else {
            const float nAre = are * Are - aim * Aim;
            const float nAim = are * Aim + aim * Are;
            Are = nAre; Aim = nAim;
        }
    }

    if (!WRITE_X)
        Agg[p * NCHUNK + c] = make_float4(Are, Aim, xre, xim);
}

// ---------------------------------------------------------------------------
// Carry scan via shfl (proven r7).
// ---------------------------------------------------------------------------
struct CT { float Ar, Ai, br, bi; };   // x -> A*x + b  (complex)

__device__ __forceinline__ CT ct_compose(const CT& f, const CT& s) {
    CT r;
    r.Ar = s.Ar * f.Ar - s.Ai * f.Ai;
    r.Ai = s.Ar * f.Ai + s.Ai * f.Ar;
    r.br = s.Ar * f.br - s.Ai * f.bi + s.br;
    r.bi = s.Ar * f.bi + s.Ai * f.br + s.bi;
    return r;
}

__global__ __launch_bounds__(256) void carry_shfl_kernel(
    const float4* __restrict__ Agg,   // P x NCHUNK
    float2* __restrict__ Carry)       // NCHUNK x P
{
    const int pch = blockIdx.x;
    const int t  = threadIdx.x;
    const int ln = t & 63;
    const int wv = t >> 6;

    __shared__ float4 wtot[4];

    CT v[4];
    #pragma unroll
    for (int i = 0; i < 4; ++i) {
        float4 f = Agg[(size_t)pch * NCHUNK + 4 * t + i];
        v[i].Ar = f.x; v[i].Ai = f.y; v[i].br = f.z; v[i].bi = f.w;
    }
    CT val = v[0];
    #pragma unroll
    for (int i = 1; i < 4; ++i) val = ct_compose(val, v[i]);

    #pragma unroll
    for (int off = 1; off < 64; off <<= 1) {
        CT o;
        o.Ar = __shfl_up(val.Ar, off);
        o.Ai = __shfl_up(val.Ai, off);
        o.br = __shfl_up(val.br, off);
        o.bi = __shfl_up(val.bi, off);
        if (ln >= off) val = ct_compose(o, val);
    }

    CT lexcl;
    lexcl.Ar = __shfl_up(val.Ar, 1);
    lexcl.Ai = __shfl_up(val.Ai, 1);
    lexcl.br = __shfl_up(val.br, 1);
    lexcl.bi = __shfl_up(val.bi, 1);
    if (ln == 0) { lexcl.Ar = 1.f; lexcl.Ai = 0.f; lexcl.br = 0.f; lexcl.bi = 0.f; }

    if (ln == 63) wtot[wv] = make_float4(val.Ar, val.Ai, val.br, val.bi);
    __syncthreads();

    CT wpre; wpre.Ar = 1.f; wpre.Ai = 0.f; wpre.br = 0.f; wpre.bi = 0.f;
    for (int i = 0; i < wv; ++i) {
        float4 f = wtot[i];
        CT tt; tt.Ar = f.x; tt.Ai = f.y; tt.br = f.z; tt.bi = f.w;
        wpre = ct_compose(wpre, tt);
    }

    CT E = ct_compose(wpre, lexcl);
    #pragma unroll
    for (int i = 0; i < 4; ++i) {
        Carry[(size_t)(4 * t + i) * P_DIM + pch] = make_float2(E.br, E.bi);
        E = ct_compose(E, v[i]);
    }
}

extern "C" void kernel_launch(void* const* d_in, const int* in_sizes, int n_in,
                              void* d_out, int out_size, void* d_ws, size_t ws_size,
                              hipStream_t stream) {
    const float* U       = (const float*)d_in[0];
    const float* dts     = (const float*)d_in[1];
    const float* Lre     = (const float*)d_in[2];
    const float* Lim     = (const float*)d_in[3];
    const float* Bre     = (const float*)d_in[4];
    const float* Bim     = (const float*)d_in[5];
    const float* Cre     = (const float*)d_in[6];
    const float* Cim     = (const float*)d_in[7];
    const float* Dv      = (const float*)d_in[8];
    const float* logstep = (const float*)d_in[9];
    float* out = (float*)d_out;

    char* ws = (char*)d_ws;
    __bf16* G2 = (__bf16*)ws;                                 // L x 512 bf16
    __bf16* B2 = (__bf16*)(ws + (size_t)L_SEQ * 512 * 2);
    __bf16* C2 = B2 + 512 * 512;
    float4* Agg = (float4*)(C2 + 512 * 512);
    float2* Carry = (float2*)(Agg + (size_t)P_DIM * NCHUNK);

    build_kernel<<<768, 512, 0, stream>>>(Bre, Bim, Cre, Cim, B2, C2);

    dim3 g1(L_SEQ / 128, 4);
    gemm1_kernel<<<g1, 256, 0, stream>>>(U, B2, G2);

    unsigned int* G2u = (unsigned int*)G2;
    scan_chunk_kernel<0><<<NCHUNK, 256, 0, stream>>>(
        dts, Lre, Lim, logstep, G2u, Agg, nullptr);
    carry_shfl_kernel<<<P_DIM, 256, 0, stream>>>(Agg, Carry);
    scan_chunk_kernel<1><<<NCHUNK, 256, 0, stream>>>(
        dts, Lre, Lim, logstep, G2u, nullptr, Carry);

    dim3 g2(L_SEQ / 128, 4);
    gemm2_kernel<<<g2, 256, 0, stream>>>(G2, C2, out, U, Dv);
}